// Round 9
// baseline (220.074 us; speedup 1.0000x reference)
//
#include <hip/hip_runtime.h>
#include <hip/hip_bf16.h>

// DenseAttentionMultiHead: out_h = Q_h @ G_bh, Q = x@W^T, G_bh = X_h^T X_h.
// B=4, S=2048, H=1024, heads=16, hd=64. 19.9 GFLOP total.
// 2 plain stream launches (cooperative launch does NOT work in this harness):
//   gx_partial: W->bf16 + x->bf16 + G partials via MFMA (8 chunks x 64 bh),
//               then intra-kernel device barrier (512 blocks co-resident by
//               construction) + folded G reduce -> Gb bf16
//   gemm_qout:  Q GEMM (128x128, BK=64, global_load_lds, XOR-swizzled LDS,
//               16x16x32 MFMA) + fused @G epilogue. Grid = (mb, nb) so that
//               XCD = mb%8: the 8 n-blocks sharing an A-tile stay XCD-local.

typedef __bf16 bf16x8 __attribute__((ext_vector_type(8)));
typedef float f32x4 __attribute__((ext_vector_type(4)));

typedef __attribute__((address_space(3))) unsigned int lds_u32;
typedef const __attribute__((address_space(1))) unsigned int glb_u32;

__device__ __forceinline__ void gld_lds16(const void* g, void* l) {
    // async global->LDS, 16 B/lane; LDS dest = wave-uniform base + lane*16
    __builtin_amdgcn_global_load_lds((glb_u32*)g, (lds_u32*)l, 16, 0, 0);
}

__device__ __forceinline__ unsigned short f2bf(float f) {
    unsigned int u = __float_as_uint(f);
    u += 0x7FFFu + ((u >> 16) & 1u);   // RNE; inputs finite
    return (unsigned short)(u >> 16);
}

#define XT_S 136

// ---------------------------------------------------------------- W + x convert + G partials + reduce
// grid (8 chunks, 64 bh) = 512 blocks, all co-resident (2/CU: 17KB LDS, lb(256,2)).
// Each block:
//   1) converts its 2048-element slice of W (8 floats/thread)
//   2) two 128-row passes: load x tile, convert->xb global + xt transposed LDS,
//      accumulate G_partial = Xt @ X via MFMA (K=128 per pass) -> Gp
//   3) device barrier (counter + fences, G16), then reduce its 512-element
//      slice of G_bh over the 8 chunks -> Gb bf16 (same sums as old g_reduce)
__global__ __launch_bounds__(256, 2) void gx_partial(
        const float* __restrict__ x, const float* __restrict__ W,
        unsigned short* __restrict__ xb, unsigned short* __restrict__ Wb,
        float* __restrict__ Gp, unsigned short* __restrict__ Gb,
        unsigned* __restrict__ ctr) {
    __shared__ __align__(16) unsigned short xt[64 * XT_S];  // 64 d x 128 s
    const int tid = threadIdx.x;
    const int chunk = blockIdx.x;     // 0..7
    const int bh = blockIdx.y;        // 0..63
    const int fb = bh * 8 + chunk;    // 0..511 flat block id for W slice
    const int b = bh >> 4, h = bh & 15;
    const int wave = tid >> 6, lane = tid & 63;
    const int lm = lane & 15, quad = lane >> 4;

    // ---- W convert: 512 blocks x 256 thr x 8 = 1M elements
    {
        size_t base = (size_t)fb * 2048 + (size_t)tid * 8;
        float4 v0 = *(const float4*)&W[base];
        float4 v1 = *(const float4*)&W[base + 4];
        ushort4 o0 = {f2bf(v0.x), f2bf(v0.y), f2bf(v0.z), f2bf(v0.w)};
        ushort4 o1 = {f2bf(v1.x), f2bf(v1.y), f2bf(v1.z), f2bf(v1.w)};
        *(ushort4*)&Wb[base] = o0;
        *(ushort4*)&Wb[base + 4] = o1;
    }

    // ---- x convert + G partials over 256 rows (two 128-row passes)
    f32x4 acc[4] = {};
    for (int half = 0; half < 2; ++half) {
        const size_t gbase =
            ((size_t)(b * 2048 + chunk * 256 + half * 128)) * 1024 + h * 64;
        __syncthreads();
        #pragma unroll
        for (int i = 0; i < 8; ++i) {
            int idx = tid + 256 * i;  // 128 s x 16 float4
            int s = idx >> 4;
            int c = (idx & 15) * 4;
            float4 v = *(const float4*)&x[gbase + (size_t)s * 1024 + c];
            ushort4 o = {f2bf(v.x), f2bf(v.y), f2bf(v.z), f2bf(v.w)};
            *(ushort4*)&xb[gbase + (size_t)s * 1024 + c] = o;
            xt[(c + 0) * XT_S + s] = o.x;
            xt[(c + 1) * XT_S + s] = o.y;
            xt[(c + 2) * XT_S + s] = o.z;
            xt[(c + 3) * XT_S + s] = o.w;
        }
        __syncthreads();
        // wave w computes G rows [w*16, w*16+16) x all 64 cols, K=128
        #pragma unroll
        for (int k = 0; k < 4; ++k) {
            bf16x8 af = *(const bf16x8*)&xt[(wave * 16 + lm) * XT_S + k * 32 + quad * 8];
            #pragma unroll
            for (int ni = 0; ni < 4; ++ni) {
                bf16x8 bg = *(const bf16x8*)&xt[(ni * 16 + lm) * XT_S + k * 32 + quad * 8];
                acc[ni] = __builtin_amdgcn_mfma_f32_16x16x32_bf16(af, bg, acc[ni], 0, 0, 0);
            }
        }
    }
    float* gp = Gp + ((size_t)(chunk * 64 + bh)) * 4096;
    #pragma unroll
    for (int ni = 0; ni < 4; ++ni)
        #pragma unroll
        for (int r = 0; r < 4; ++r)
            gp[(wave * 16 + quad * 4 + r) * 64 + ni * 16 + lm] = acc[ni][r];

    // ---- intra-kernel device barrier (all 512 blocks co-resident)
    __threadfence();                  // release Gp writes, device scope
    __syncthreads();
    if (tid == 0) {
        atomicAdd(ctr, 1u);
        int guard = 1 << 22;          // visible-failure guard, never hit legit
        while (atomicAdd(ctr, 0u) < 512u && --guard) ;
        __threadfence();              // acquire other blocks' Gp writes
    }
    __syncthreads();

    // ---- folded reduce: this block sums elems [chunk*512, +512) of G_bh
    {
        int e0 = chunk * 512 + tid * 2;
        float2 s = {0.f, 0.f};
        #pragma unroll
        for (int c = 0; c < 8; ++c) {
            float2 v = *(const float2*)&Gp[((size_t)(c * 64 + bh)) * 4096 + e0];
            s.x += v.x; s.y += v.y;
        }
        ushort2 o = {f2bf(s.x), f2bf(s.y)};
        *(ushort2*)&Gb[(size_t)bh * 4096 + e0] = o;
    }
}

// ---------------------------------------------------------------- Q GEMM + @G epilogue
// M=8192, N=1024, K=1024; 128x128 tile, BK=64, global_load_lds staging.
// LDS layout XOR-swizzled: LDS(r, j) holds global(r, j^(r&7)), j = 16B block.
// Grid (mb=64, nb=8): XCD = flat%8 = mb%8, so all 8 n-blocks reading the
// same A-tile are on one XCD (A LLC->L2 refill 128MB -> 16MB).
// Epilogue: each wave's 64x64 Q quadrant spans exactly one head's columns;
// C-layout -> A-layout via wave-private LDS (stride 136), B = G read row-wise
// (G symmetric), 32 extra MFMA/wave. out fp32.
__global__ __launch_bounds__(256, 2) void gemm_qout(
        const unsigned short* __restrict__ xb, const unsigned short* __restrict__ Wb,
        const unsigned short* __restrict__ Gb, float* __restrict__ out) {
    __shared__ __align__(16) unsigned short smem[26624];  // 52 KB
    unsigned short* lA = smem;            // [0, 8192)        128x64 (swizzled)
    unsigned short* lB = smem + 8192;     // [8192, 16384)    128x64 (swizzled)
    unsigned short* Qt = smem;            // [0, 17408)  128 x stride 136 (post-loop)
    unsigned short* G2 = smem + 17408;    // [17408, 26624)   2 x 64 x stride 72
    const int tid = threadIdx.x;
    const int m0 = blockIdx.x * 128;      // mb = blockIdx.x (0..63)
    const int n0 = blockIdx.y * 128;      // nb = blockIdx.y (0..7)
    const int b  = blockIdx.x >> 4;
    const int h0 = blockIdx.y * 2;
    const int lane = tid & 63, wave = tid >> 6;
    const int wr = (wave >> 1) * 64, wc = (wave & 1) * 64;
    const int lm = lane & 15, quad = lane >> 4;
    const int srow = wave * 32 + (lane >> 3);
    // swizzled global source column: lane writes LDS block j=lane&7 at row r;
    // its global block is j ^ (r&7), r&7 == (lane>>3)&7
    const int scol = (((lane & 7) ^ ((lane >> 3) & 7))) * 8;

    // stage both heads' G (bf16) into padded LDS (disjoint from lA/lB)
    #pragma unroll
    for (int i = 0; i < 4; ++i) {
        int idx = tid + 256 * i;          // 2 heads x 64 rows x 8 chunks
        int hh = idx >> 9;
        int rr = (idx >> 3) & 63;
        int cc = (idx & 7) * 8;
        *(uint4*)&G2[hh * 4608 + rr * 72 + cc] =
            *(const uint4*)&Gb[((size_t)(b * 16 + h0 + hh)) * 4096 + rr * 64 + cc];
    }

    f32x4 acc[4][4] = {};
    for (int kt = 0; kt < 1024; kt += 64) {
        const unsigned short* ga = &xb[(size_t)(m0 + srow) * 1024 + kt + scol];
        const unsigned short* gb = &Wb[(size_t)(n0 + srow) * 1024 + kt + scol];
        #pragma unroll
        for (int i = 0; i < 4; ++i) {     // rows += 8 keeps (r&7) invariant
            gld_lds16(ga + (size_t)i * 8 * 1024, &lA[(wave * 32 + i * 8) * 64]);
            gld_lds16(gb + (size_t)i * 8 * 1024, &lB[(wave * 32 + i * 8) * 64]);
        }
        __syncthreads();
        #pragma unroll
        for (int kk = 0; kk < 2; ++kk) {
            bf16x8 af[4], bg[4];
            #pragma unroll
            for (int mi = 0; mi < 4; ++mi) {
                int ra = wr + mi * 16 + lm;                 // ra&7 == lm&7
                int jb = (kk * 4 + quad) ^ (ra & 7);        // swizzled block
                af[mi] = *(const bf16x8*)&lA[ra * 64 + jb * 8];
            }
            #pragma unroll
            for (int ni = 0; ni < 4; ++ni) {
                int rb = wc + ni * 16 + lm;
                int jb = (kk * 4 + quad) ^ (rb & 7);
                bg[ni] = *(const bf16x8*)&lB[rb * 64 + jb * 8];
            }
            #pragma unroll
            for (int mi = 0; mi < 4; ++mi)
                #pragma unroll
                for (int ni = 0; ni < 4; ++ni)
                    acc[mi][ni] = __builtin_amdgcn_mfma_f32_16x16x32_bf16(
                        af[mi], bg[ni], acc[mi][ni], 0, 0, 0);
        }
        __syncthreads();
    }
    // epilogue: Qt(bf16) in wave-private quadrant; no extra barrier needed
    // (final loop barrier done; each wave reads only what it wrote)
    #pragma unroll
    for (int mi = 0; mi < 4; ++mi)
        #pragma unroll
        for (int ni = 0; ni < 4; ++ni)
            #pragma unroll
            for (int r = 0; r < 4; ++r)
                Qt[(wr + mi * 16 + quad * 4 + r) * 136 + wc + ni * 16 + lm] =
                    f2bf(acc[mi][ni][r]);
    #pragma unroll
    for (int mi = 0; mi < 4; ++mi)
        #pragma unroll
        for (int ni = 0; ni < 4; ++ni)
            acc[mi][ni] = (f32x4){0.f, 0.f, 0.f, 0.f};
    const int hh = wave & 1;              // head half of this wave's columns
    #pragma unroll
    for (int kk = 0; kk < 2; ++kk) {
        bf16x8 af[4], bg[4];
        #pragma unroll
        for (int mi = 0; mi < 4; ++mi)
            af[mi] = *(const bf16x8*)&Qt[(wr + mi * 16 + lm) * 136 + wc + kk * 32 + quad * 8];
        #pragma unroll
        for (int ni = 0; ni < 4; ++ni)   // B[k][n] = G[k][n] = G[n][k] (symmetric)
            bg[ni] = *(const bf16x8*)&G2[hh * 4608 + (ni * 16 + lm) * 72 + kk * 32 + quad * 8];
        #pragma unroll
        for (int mi = 0; mi < 4; ++mi)
            #pragma unroll
            for (int ni = 0; ni < 4; ++ni)
                acc[mi][ni] = __builtin_amdgcn_mfma_f32_16x16x32_bf16(
                    af[mi], bg[ni], acc[mi][ni], 0, 0, 0);
    }
    #pragma unroll
    for (int mi = 0; mi < 4; ++mi)
        #pragma unroll
        for (int ni = 0; ni < 4; ++ni)
            #pragma unroll
            for (int r = 0; r < 4; ++r)
                out[(size_t)(m0 + wr + mi * 16 + quad * 4 + r) * 1024
                    + n0 + wc + ni * 16 + lm] = acc[mi][ni][r];
}

// ---------------------------------------------------------------- launch
extern "C" void kernel_launch(void* const* d_in, const int* in_sizes, int n_in,
                              void* d_out, int out_size, void* d_ws, size_t ws_size,
                              hipStream_t stream) {
    const float* x = (const float*)d_in[0];   // [4,2048,1024] fp32
    const float* W = (const float*)d_in[1];   // [1024,1024] fp32
    float* out = (float*)d_out;               // [4,2048,1024] fp32
    char* ws = (char*)d_ws;
    unsigned short* xb = (unsigned short*)(ws);              // 16 MB  x bf16
    unsigned short* Wb = (unsigned short*)(ws + 16777216);   //  2 MB  W bf16
    float*          Gp = (float*)        (ws + 18874368);    //  8 MB  G partials fp32
    unsigned short* Gb = (unsigned short*)(ws + 27262976);   // 0.5 MB G bf16
    unsigned*       ctr = (unsigned*)    (ws + 27787264);    // 64 B barrier counter

    hipMemsetAsync(ctr, 0, 64, stream);       // zero the barrier counter
    gx_partial<<<dim3(8, 64), 256, 0, stream>>>(x, W, xb, Wb, Gp, Gb, ctr);
    gemm_qout<<<dim3(64, 8), 256, 0, stream>>>(xb, Wb, Gb, out);
}

// Round 10
// 111.750 us; speedup vs baseline: 1.9693x; 1.9693x over previous
//
#include <hip/hip_runtime.h>
#include <hip/hip_bf16.h>

// DenseAttentionMultiHead: out_h = Q_h @ G_bh, Q = x@W^T, G_bh = X_h^T X_h.
// B=4, S=2048, H=1024, heads=16, hd=64. 19.9 GFLOP total.
// 3 plain stream launches (cooperative launch and atomic-spin device barriers
// both FAIL in this harness -- R4: never executed; R9: atomic RMW spin
// congested the fabric, 420 GB/s HBM, +106 us):
//   gx_partial: W->bf16 + x->bf16 + G partials via MFMA (8 chunks x 64 bh)
//   g_reduce:   Gp (8 chunks) -> Gb bf16
//   gemm_qout:  Q GEMM (128x128, BK=64, global_load_lds, XOR-swizzled LDS,
//               16x16x32 MFMA) + fused @G epilogue. Grid = (mb, nb) so that
//               XCD = mb%8: the 8 n-blocks sharing an A-tile stay XCD-local.

typedef __bf16 bf16x8 __attribute__((ext_vector_type(8)));
typedef float f32x4 __attribute__((ext_vector_type(4)));

typedef __attribute__((address_space(3))) unsigned int lds_u32;
typedef const __attribute__((address_space(1))) unsigned int glb_u32;

__device__ __forceinline__ void gld_lds16(const void* g, void* l) {
    // async global->LDS, 16 B/lane; LDS dest = wave-uniform base + lane*16
    __builtin_amdgcn_global_load_lds((glb_u32*)g, (lds_u32*)l, 16, 0, 0);
}

__device__ __forceinline__ unsigned short f2bf(float f) {
    unsigned int u = __float_as_uint(f);
    u += 0x7FFFu + ((u >> 16) & 1u);   // RNE; inputs finite
    return (unsigned short)(u >> 16);
}

#define XT_S 136

// ---------------------------------------------------------------- W + x convert + G partials
// grid (8 chunks, 64 bh) = 512 blocks. Each block:
//   1) converts its 2048-element slice of W (8 floats/thread)
//   2) two 128-row passes: load x tile, convert->xb global + xt transposed LDS,
//      accumulate G_partial = Xt @ X via MFMA (K=128 per pass)
__global__ __launch_bounds__(256) void gx_partial(
        const float* __restrict__ x, const float* __restrict__ W,
        unsigned short* __restrict__ xb, unsigned short* __restrict__ Wb,
        float* __restrict__ Gp) {
    __shared__ __align__(16) unsigned short xt[64 * XT_S];  // 64 d x 128 s
    const int tid = threadIdx.x;
    const int chunk = blockIdx.x;     // 0..7
    const int bh = blockIdx.y;        // 0..63
    const int fb = bh * 8 + chunk;    // 0..511 flat block id for W slice
    const int b = bh >> 4, h = bh & 15;
    const int wave = tid >> 6, lane = tid & 63;
    const int lm = lane & 15, quad = lane >> 4;

    // ---- W convert: 512 blocks x 256 thr x 8 = 1M elements
    {
        size_t base = (size_t)fb * 2048 + (size_t)tid * 8;
        float4 v0 = *(const float4*)&W[base];
        float4 v1 = *(const float4*)&W[base + 4];
        ushort4 o0 = {f2bf(v0.x), f2bf(v0.y), f2bf(v0.z), f2bf(v0.w)};
        ushort4 o1 = {f2bf(v1.x), f2bf(v1.y), f2bf(v1.z), f2bf(v1.w)};
        *(ushort4*)&Wb[base] = o0;
        *(ushort4*)&Wb[base + 4] = o1;
    }

    // ---- x convert + G partials over 256 rows (two 128-row passes)
    f32x4 acc[4] = {};
    for (int half = 0; half < 2; ++half) {
        const size_t gbase =
            ((size_t)(b * 2048 + chunk * 256 + half * 128)) * 1024 + h * 64;
        __syncthreads();
        #pragma unroll
        for (int i = 0; i < 8; ++i) {
            int idx = tid + 256 * i;  // 128 s x 16 float4
            int s = idx >> 4;
            int c = (idx & 15) * 4;
            float4 v = *(const float4*)&x[gbase + (size_t)s * 1024 + c];
            ushort4 o = {f2bf(v.x), f2bf(v.y), f2bf(v.z), f2bf(v.w)};
            *(ushort4*)&xb[gbase + (size_t)s * 1024 + c] = o;
            xt[(c + 0) * XT_S + s] = o.x;
            xt[(c + 1) * XT_S + s] = o.y;
            xt[(c + 2) * XT_S + s] = o.z;
            xt[(c + 3) * XT_S + s] = o.w;
        }
        __syncthreads();
        // wave w computes G rows [w*16, w*16+16) x all 64 cols, K=128
        #pragma unroll
        for (int k = 0; k < 4; ++k) {
            bf16x8 af = *(const bf16x8*)&xt[(wave * 16 + lm) * XT_S + k * 32 + quad * 8];
            #pragma unroll
            for (int ni = 0; ni < 4; ++ni) {
                bf16x8 bg = *(const bf16x8*)&xt[(ni * 16 + lm) * XT_S + k * 32 + quad * 8];
                acc[ni] = __builtin_amdgcn_mfma_f32_16x16x32_bf16(af, bg, acc[ni], 0, 0, 0);
            }
        }
    }
    float* gp = Gp + ((size_t)(chunk * 64 + bh)) * 4096;
    #pragma unroll
    for (int ni = 0; ni < 4; ++ni)
        #pragma unroll
        for (int r = 0; r < 4; ++r)
            gp[(wave * 16 + quad * 4 + r) * 64 + ni * 16 + lm] = acc[ni][r];
}

// ---------------------------------------------------------------- G reduce
// G_bf16[bh][4096] = sum over 8 chunks. grid (64,4) x 256, float4/thread.
__global__ __launch_bounds__(256) void g_reduce(
        const float* __restrict__ Gp, unsigned short* __restrict__ Gb) {
    const int bh = blockIdx.x;
    const int e0 = blockIdx.y * 1024 + threadIdx.x * 4;
    float4 s = {0.f, 0.f, 0.f, 0.f};
    #pragma unroll
    for (int c = 0; c < 8; ++c) {
        float4 v = *(const float4*)&Gp[((size_t)(c * 64 + bh)) * 4096 + e0];
        s.x += v.x; s.y += v.y; s.z += v.z; s.w += v.w;
    }
    ushort4 o;
    o.x = f2bf(s.x); o.y = f2bf(s.y); o.z = f2bf(s.z); o.w = f2bf(s.w);
    *(ushort4*)&Gb[(size_t)bh * 4096 + e0] = o;
}

// ---------------------------------------------------------------- Q GEMM + @G epilogue
// M=8192, N=1024, K=1024; 128x128 tile, BK=64, global_load_lds staging.
// LDS layout XOR-swizzled: LDS(r, j) holds global(r, j^(r&7)), j = 16B block.
// Grid (mb=64, nb=8): XCD = flat%8 = mb%8, so all 8 n-blocks reading the
// same A-tile are on one XCD (A LLC->L2 refill 128MB -> 16MB).
// Epilogue: each wave's 64x64 Q quadrant spans exactly one head's columns;
// C-layout -> A-layout via wave-private LDS (stride 136), B = G read row-wise
// (G symmetric), 32 extra MFMA/wave. out fp32.
__global__ __launch_bounds__(256, 2) void gemm_qout(
        const unsigned short* __restrict__ xb, const unsigned short* __restrict__ Wb,
        const unsigned short* __restrict__ Gb, float* __restrict__ out) {
    __shared__ __align__(16) unsigned short smem[26624];  // 52 KB
    unsigned short* lA = smem;            // [0, 8192)        128x64 (swizzled)
    unsigned short* lB = smem + 8192;     // [8192, 16384)    128x64 (swizzled)
    unsigned short* Qt = smem;            // [0, 17408)  128 x stride 136 (post-loop)
    unsigned short* G2 = smem + 17408;    // [17408, 26624)   2 x 64 x stride 72
    const int tid = threadIdx.x;
    const int m0 = blockIdx.x * 128;      // mb = blockIdx.x (0..63)
    const int n0 = blockIdx.y * 128;      // nb = blockIdx.y (0..7)
    const int b  = blockIdx.x >> 4;
    const int h0 = blockIdx.y * 2;
    const int lane = tid & 63, wave = tid >> 6;
    const int wr = (wave >> 1) * 64, wc = (wave & 1) * 64;
    const int lm = lane & 15, quad = lane >> 4;
    const int srow = wave * 32 + (lane >> 3);
    // swizzled global source column: lane writes LDS block j=lane&7 at row r;
    // its global block is j ^ (r&7), r&7 == (lane>>3)&7
    const int scol = (((lane & 7) ^ ((lane >> 3) & 7))) * 8;

    // stage both heads' G (bf16) into padded LDS (disjoint from lA/lB)
    #pragma unroll
    for (int i = 0; i < 4; ++i) {
        int idx = tid + 256 * i;          // 2 heads x 64 rows x 8 chunks
        int hh = idx >> 9;
        int rr = (idx >> 3) & 63;
        int cc = (idx & 7) * 8;
        *(uint4*)&G2[hh * 4608 + rr * 72 + cc] =
            *(const uint4*)&Gb[((size_t)(b * 16 + h0 + hh)) * 4096 + rr * 64 + cc];
    }

    f32x4 acc[4][4] = {};
    for (int kt = 0; kt < 1024; kt += 64) {
        const unsigned short* ga = &xb[(size_t)(m0 + srow) * 1024 + kt + scol];
        const unsigned short* gb = &Wb[(size_t)(n0 + srow) * 1024 + kt + scol];
        #pragma unroll
        for (int i = 0; i < 4; ++i) {     // rows += 8 keeps (r&7) invariant
            gld_lds16(ga + (size_t)i * 8 * 1024, &lA[(wave * 32 + i * 8) * 64]);
            gld_lds16(gb + (size_t)i * 8 * 1024, &lB[(wave * 32 + i * 8) * 64]);
        }
        __syncthreads();
        #pragma unroll
        for (int kk = 0; kk < 2; ++kk) {
            bf16x8 af[4], bg[4];
            #pragma unroll
            for (int mi = 0; mi < 4; ++mi) {
                int ra = wr + mi * 16 + lm;                 // ra&7 == lm&7
                int jb = (kk * 4 + quad) ^ (ra & 7);        // swizzled block
                af[mi] = *(const bf16x8*)&lA[ra * 64 + jb * 8];
            }
            #pragma unroll
            for (int ni = 0; ni < 4; ++ni) {
                int rb = wc + ni * 16 + lm;
                int jb = (kk * 4 + quad) ^ (rb & 7);
                bg[ni] = *(const bf16x8*)&lB[rb * 64 + jb * 8];
            }
            #pragma unroll
            for (int mi = 0; mi < 4; ++mi)
                #pragma unroll
                for (int ni = 0; ni < 4; ++ni)
                    acc[mi][ni] = __builtin_amdgcn_mfma_f32_16x16x32_bf16(
                        af[mi], bg[ni], acc[mi][ni], 0, 0, 0);
        }
        __syncthreads();
    }
    // epilogue: Qt(bf16) in wave-private quadrant; no extra barrier needed
    // (final loop barrier done; each wave reads only what it wrote)
    #pragma unroll
    for (int mi = 0; mi < 4; ++mi)
        #pragma unroll
        for (int ni = 0; ni < 4; ++ni)
            #pragma unroll
            for (int r = 0; r < 4; ++r)
                Qt[(wr + mi * 16 + quad * 4 + r) * 136 + wc + ni * 16 + lm] =
                    f2bf(acc[mi][ni][r]);
    #pragma unroll
    for (int mi = 0; mi < 4; ++mi)
        #pragma unroll
        for (int ni = 0; ni < 4; ++ni)
            acc[mi][ni] = (f32x4){0.f, 0.f, 0.f, 0.f};
    const int hh = wave & 1;              // head half of this wave's columns
    #pragma unroll
    for (int kk = 0; kk < 2; ++kk) {
        bf16x8 af[4], bg[4];
        #pragma unroll
        for (int mi = 0; mi < 4; ++mi)
            af[mi] = *(const bf16x8*)&Qt[(wr + mi * 16 + lm) * 136 + wc + kk * 32 + quad * 8];
        #pragma unroll
        for (int ni = 0; ni < 4; ++ni)   // B[k][n] = G[k][n] = G[n][k] (symmetric)
            bg[ni] = *(const bf16x8*)&G2[hh * 4608 + (ni * 16 + lm) * 72 + kk * 32 + quad * 8];
        #pragma unroll
        for (int mi = 0; mi < 4; ++mi)
            #pragma unroll
            for (int ni = 0; ni < 4; ++ni)
                acc[mi][ni] = __builtin_amdgcn_mfma_f32_16x16x32_bf16(
                    af[mi], bg[ni], acc[mi][ni], 0, 0, 0);
    }
    #pragma unroll
    for (int mi = 0; mi < 4; ++mi)
        #pragma unroll
        for (int ni = 0; ni < 4; ++ni)
            #pragma unroll
            for (int r = 0; r < 4; ++r)
                out[(size_t)(m0 + wr + mi * 16 + quad * 4 + r) * 1024
                    + n0 + wc + ni * 16 + lm] = acc[mi][ni][r];
}

// ---------------------------------------------------------------- launch
extern "C" void kernel_launch(void* const* d_in, const int* in_sizes, int n_in,
                              void* d_out, int out_size, void* d_ws, size_t ws_size,
                              hipStream_t stream) {
    const float* x = (const float*)d_in[0];   // [4,2048,1024] fp32
    const float* W = (const float*)d_in[1];   // [1024,1024] fp32
    float* out = (float*)d_out;               // [4,2048,1024] fp32
    char* ws = (char*)d_ws;
    unsigned short* xb = (unsigned short*)(ws);              // 16 MB  x bf16
    unsigned short* Wb = (unsigned short*)(ws + 16777216);   //  2 MB  W bf16
    float*          Gp = (float*)        (ws + 18874368);    //  8 MB  G partials fp32
    unsigned short* Gb = (unsigned short*)(ws + 27262976);   // 0.5 MB G bf16

    gx_partial<<<dim3(8, 64), 256, 0, stream>>>(x, W, xb, Wb, Gp);
    g_reduce<<<dim3(64, 4), 256, 0, stream>>>(Gp, Gb);
    gemm_qout<<<dim3(64, 8), 256, 0, stream>>>(xb, Wb, Gb, out);
}